// Round 11
// baseline (227.852 us; speedup 1.0000x reference)
//
#include <hip/hip_runtime.h>
#include <math.h>

#define T_NTIME  2048
#define T_NBATCH 128
#define T_INSIZE 512
#define T_SIZE   16
#define T_NROWS  (T_NTIME * T_NBATCH)
#define MAT_STRIDE 24

typedef __attribute__((ext_vector_type(8))) short s8v;    // 8 bf16
typedef __attribute__((ext_vector_type(4))) float f32x4;  // MFMA acc

__device__ __forceinline__ float sp_f(float v) {
  return fmaxf(v, 0.0f) + log1pf(__expf(-fabsf(v)));
}
__device__ __forceinline__ float tanh5_f(float v) {
  float a = fabsf(v);
  float e = __expf(-2.0f * a);
  float t = (1.0f - e) / (1.0f + e);
  return copysignf(5.0f * t, v);
}
__device__ __forceinline__ float lae_f(float a, float c) {
  float m = fmaxf(a, c);
  return m + log1pf(__expf(-fabsf(a - c)));
}
// RNE-pack two f32 into one uint of 2 bf16 (lo = a, hi = b)
__device__ __forceinline__ unsigned pack2(float a, float b) {
  unsigned ua = __float_as_uint(a), ub = __float_as_uint(b);
  ua = (ua + 0x7fffu + ((ua >> 16) & 1u)) >> 16;
  ub = (ub + 0x7fffu + ((ub >> 16) & 1u)) & 0xffff0000u;
  return ua | ub;
}
// async global->LDS, 16B/lane; LDS dest wave-uniform base + lane*16
__device__ __forceinline__ void gl_lds16(const float* g, float* lds) {
  __builtin_amdgcn_global_load_lds(
      (const __attribute__((address_space(1))) void*)g,
      (__attribute__((address_space(3))) void*)lds, 16, 0, 0);
}

// ---------- K1: depth-3 pipelined wave-autonomous MFMA GEMM ----------
// Wave owns 128 rows = 8 tiles(16 rows) x 16 K-steps(32k) = 128 steps.
// Quad-buffered 2KB step buffers; prefetch 3 steps ahead (12KB/wave in
// flight); counted vmcnt(6) + sched_barrier(0). W in LDS as bf16 (16KB),
// single-chain MFMA (error ~2^-8.5, threshold 0.18: safe).
__global__ __launch_bounds__(256, 3)
void k1_deep(const float* __restrict__ x, const float* __restrict__ W,
             const float* __restrict__ bias, float* __restrict__ out) {
  __shared__ uint4 wp[16][64];           // 16 KB: row s, slot g8^(s&7)
  __shared__ float xb[4][4][16][32];     // 32 KB: [wave][buf][row][k]
  const int tid = threadIdx.x;

  // one-time W pack to bf16 (coalesced read, swizzled LDS write)
  {
#pragma unroll
    for (int k = 0; k < 4; ++k) {
      const int g = tid + k * 256;        // 8-float group, 1024 total
      const int s = g >> 6;
      const int g8 = g & 63;
      const float4 a0 = *(const float4*)(W + g * 8);
      const float4 a1 = *(const float4*)(W + g * 8 + 4);
      uint4 p;
      p.x = pack2(a0.x, a0.y);
      p.y = pack2(a0.z, a0.w);
      p.z = pack2(a1.x, a1.y);
      p.w = pack2(a1.z, a1.w);
      wp[s][g8 ^ (s & 7)] = p;
    }
  }
  __syncthreads();

  const int l = tid & 63;
  const int w = tid >> 6;
  const int lr = l & 15;        // fragment row (x-row in tile / W row)
  const int lk = (l >> 4) & 3;  // k-subgroup
  const int r7 = lr & 7;

  const long rowbase = ((long)blockIdx.x * 4 + w) * 128;
  float* xw = &xb[w][0][0][0];
  const float4 bv = *(const float4*)(bias + lk * 4);

  // per-lane swizzled global base: instr0 covers rows 0-7, instr1 rows 8-15
  const int r0 = l >> 3;
  const int kd = (l & 7) ^ (r0 & 7);     // rows r0 and r0+8 share kd
  const float* g0 = x + (rowbase + r0) * T_INSIZE + kd * 4;

#define ISSUE(S)                                                        \
  do {                                                                  \
    const long off_ = (long)((S) >> 4) * (16 * T_INSIZE) + ((S) & 15) * 32; \
    float* dst_ = xw + ((S) & 3) * 512;                                 \
    gl_lds16(g0 + off_, dst_);                                          \
    gl_lds16(g0 + off_ + 8 * T_INSIZE, dst_ + 256);                     \
  } while (0)

  ISSUE(0); ISSUE(1); ISSUE(2);

  f32x4 acc = {0.f, 0.f, 0.f, 0.f};
#pragma unroll 1
  for (int m = 0; m < 128; ++m) {        // tile = m>>4, ks = m&15
    if (m + 3 < 128) ISSUE(m + 3);
    if (m < 125)       asm volatile("s_waitcnt vmcnt(6)" ::: "memory");
    else if (m == 125) asm volatile("s_waitcnt vmcnt(4)" ::: "memory");
    else if (m == 126) asm volatile("s_waitcnt vmcnt(2)" ::: "memory");
    else               asm volatile("s_waitcnt vmcnt(0)" ::: "memory");
    __builtin_amdgcn_sched_barrier(0);

    // A-frag: W row lr, k-group g8 = (ks)*4 + lk (bf16, direct)
    union { uint4 u; s8v v; } A;
    A.u = wp[lr][(((m & 15) << 2) + lk) ^ r7];

    // B-frag: x row lr, k = lk*8..+8 from swizzled step buffer
    const float* bufr = xw + (m & 3) * 512 + lr * 32;
    const float4 b0 = *(const float4*)(bufr + (((lk << 1) | 0) ^ r7) * 4);
    const float4 b1 = *(const float4*)(bufr + (((lk << 1) | 1) ^ r7) * 4);
    union { uint4 u; s8v v; } B;
    B.u.x = pack2(b0.x, b0.y);
    B.u.y = pack2(b0.z, b0.w);
    B.u.z = pack2(b1.x, b1.y);
    B.u.w = pack2(b1.z, b1.w);

    acc = __builtin_amdgcn_mfma_f32_16x16x32_bf16(A.v, B.v, acc, 0, 0, 0);

    if ((m & 15) == 15) {
      const int tile = m >> 4;
      const float y0 = acc[0] + bv.x;
      const float y1 = acc[1] + bv.y;
      const float y2 = acc[2] + bv.z;
      const float y3 = acc[3] + bv.w;
      float4 o;
      if (lk == 0) {
        o.x = 1.0f + sp_f(y0); o.y = 1.0f + sp_f(y1);
        o.z = 1.0f + sp_f(y2); o.w = 1.0f + sp_f(y3);
      } else if (lk == 1) {
        o.x = 0.1f + sp_f(y0); o.y = 0.1f + sp_f(y1);
        o.z = 0.1f + sp_f(y2); o.w = 0.1f + sp_f(y3);
      } else {
        o.x = tanh5_f(y0); o.y = tanh5_f(y1);
        o.z = tanh5_f(y2); o.w = tanh5_f(y3);
      }
      *(float4*)(out + (rowbase + (long)tile * 16 + lr) * T_SIZE + lk * 4) = o;
      acc[0] = 0.f; acc[1] = 0.f; acc[2] = 0.f; acc[3] = 0.f;
    }
  }
#undef ISSUE
}

// ---------- K2a: per-(b, chunk, basis-col) chunk transfer-matrix columns ----------
__global__ void k_scan_chunks(const float* __restrict__ out, float* __restrict__ mats,
                              int nchunks) {
  const int gtid = blockIdx.x * blockDim.x + threadIdx.x;
  const int colslot = gtid & 7;
  const int b = (gtid >> 3) & (T_NBATCH - 1);
  const int chunk = gtid >> 10;
  if (chunk >= nchunks) return;
  if (colslot >= 5) return;

  const int steps = T_NTIME / nchunks;
  const int t0 = chunk * steps;
  const float NEG = -1e30f;
  float f0 = (colslot == 0) ? 0.0f : NEG;
  float f1 = (colslot == 1) ? 0.0f : NEG;
  float f2 = (colslot == 2) ? 0.0f : NEG;
  float f3 = (colslot == 3) ? 0.0f : NEG;
  const float t4 = (colslot == 4) ? 0.0f : NEG;

  const long stride = T_NBATCH * T_SIZE;
  const float* p = out + ((long)t0 * T_NBATCH + b) * T_SIZE + 8;
  float4 mv = *(const float4*)(p);
  float4 st = *(const float4*)(p + 4);
  for (int s = 0; s < steps; ++s) {
    const float* pn = (s + 1 < steps) ? p + stride : p;
    const float4 mvn = *(const float4*)(pn);
    const float4 stn = *(const float4*)(pn + 4);

    float m, ss0, ss1, ss2, ss3;
    m = fmaxf(fmaxf(f1, f2), fmaxf(f3, t4));
    ss0 = m + __logf(__expf(f1 - m) + __expf(f2 - m) + __expf(f3 - m) + __expf(t4 - m));
    m = fmaxf(fmaxf(f0, f2), fmaxf(f3, t4));
    ss1 = m + __logf(__expf(f0 - m) + __expf(f2 - m) + __expf(f3 - m) + __expf(t4 - m));
    m = fmaxf(fmaxf(f0, f1), fmaxf(f3, t4));
    ss2 = m + __logf(__expf(f0 - m) + __expf(f1 - m) + __expf(f3 - m) + __expf(t4 - m));
    m = fmaxf(fmaxf(f0, f1), fmaxf(f2, t4));
    ss3 = m + __logf(__expf(f0 - m) + __expf(f1 - m) + __expf(f2 - m) + __expf(t4 - m));

    const float n0 = lae_f(f0 + st.x, ss0 + mv.x);
    const float n1 = lae_f(f1 + st.y, ss1 + mv.y);
    const float n2 = lae_f(f2 + st.z, ss2 + mv.z);
    const float n3 = lae_f(f3 + st.w, ss3 + mv.w);
    f0 = n0; f1 = n1; f2 = n2; f3 = n3;
    mv = mvn; st = stn; p = pn;
  }
  float* d = mats + ((long)chunk * T_NBATCH + b) * MAT_STRIDE + colslot * 4;
  float4 o; o.x = f0; o.y = f1; o.z = f2; o.w = f3;
  *(float4*)d = o;
}

// ---------- K2b: serial combine of chunk matrices per batch; logZ/T out ----------
__global__ void k_combine(const float* __restrict__ mats, float* __restrict__ logz,
                          int nchunks) {
  const int tid = threadIdx.x;
  const int i = tid & 3;
  const int b = tid >> 2;
  if (b >= T_NBATCH) return;
  float v = 0.0f;

  const float* Tb = mats + (long)b * MAT_STRIDE;
  const long cstride = (long)T_NBATCH * MAT_STRIDE;
  float q0 = Tb[i * 4 + i];
  float q1 = Tb[((i ^ 1) * 4) + i];
  float q2 = Tb[((i ^ 2) * 4) + i];
  float q3 = Tb[((i ^ 3) * 4) + i];
  float q4 = Tb[16 + i];
  for (int c = 0; c < nchunks; ++c) {
    const float* Tn = Tb + cstride;
    float n0 = 0, n1 = 0, n2 = 0, n3 = 0, n4 = 0;
    if (c + 1 < nchunks) {
      n0 = Tn[i * 4 + i];
      n1 = Tn[((i ^ 1) * 4) + i];
      n2 = Tn[((i ^ 2) * 4) + i];
      n3 = Tn[((i ^ 3) * 4) + i];
      n4 = Tn[16 + i];
    }
    const float vx1 = __shfl_xor(v, 1);
    const float vx2 = __shfl_xor(v, 2);
    const float vx3 = __shfl_xor(v, 3);
    const float a0 = q0 + v;
    const float a1 = q1 + vx1;
    const float a2 = q2 + vx2;
    const float a3 = q3 + vx3;
    const float a4 = q4;
    float m = fmaxf(fmaxf(a0, a1), fmaxf(fmaxf(a2, a3), a4));
    v = m + __logf(__expf(a0 - m) + __expf(a1 - m) + __expf(a2 - m) +
                   __expf(a3 - m) + __expf(a4 - m));
    q0 = n0; q1 = n1; q2 = n2; q3 = n3; q4 = n4;
    Tb = Tn;
  }
  float m1 = fmaxf(v, __shfl_xor(v, 1));
  m1 = fmaxf(m1, __shfl_xor(m1, 2));
  float e = __expf(v - m1);
  e += __shfl_xor(e, 1);
  e += __shfl_xor(e, 2);
  const float lz = m1 + __logf(e);
  if (i == 0) logz[b] = lz * (1.0f / (float)T_NTIME);
}

// ---------- K3: out[t][b][8..15] -= logZ[b]/T ----------
__global__ void k_sub(float* __restrict__ out, const float* __restrict__ logz) {
  const long n = (long)blockIdx.x * blockDim.x + threadIdx.x;
  if (n >= (long)T_NROWS * 2) return;
  const long tb = n >> 1;
  const int b = (int)(tb & (T_NBATCH - 1));
  const float lz = logz[b];
  float4* p = (float4*)(out + tb * T_SIZE + 8 + (n & 1) * 4);
  float4 v = *p;
  v.x -= lz; v.y -= lz; v.z -= lz; v.w -= lz;
  *p = v;
}

extern "C" void kernel_launch(void* const* d_in, const int* in_sizes, int n_in,
                              void* d_out, int out_size, void* d_ws, size_t ws_size,
                              hipStream_t stream) {
  const float* x    = (const float*)d_in[0];
  const float* W    = (const float*)d_in[1];
  const float* bias = (const float*)d_in[2];
  float* out = (float*)d_out;
  float* ws  = (float*)d_ws;

  int C = 64;
  while (C > 1 && (size_t)((long)C * T_NBATCH * MAT_STRIDE + T_NBATCH) * 4 > ws_size) C >>= 1;
  float* mats = ws;
  float* logz = ws + (long)C * T_NBATCH * MAT_STRIDE;

  k1_deep<<<512, 256, 0, stream>>>(x, W, bias, out);

  const int thr2 = C * T_NBATCH * 8;
  k_scan_chunks<<<thr2 / 256, 256, 0, stream>>>(out, mats, C);
  k_combine<<<1, 512, 0, stream>>>(mats, logz, C);
  k_sub<<<(T_NROWS * 2) / 256, 256, 0, stream>>>(out, logz);
}

// Round 12
// 222.149 us; speedup vs baseline: 1.0257x; 1.0257x over previous
//
#include <hip/hip_runtime.h>
#include <math.h>

#define T_NTIME  2048
#define T_NBATCH 128
#define T_INSIZE 512
#define T_SIZE   16
#define T_NROWS  (T_NTIME * T_NBATCH)
#define MAT_STRIDE 24
#define NCHUNK 128

typedef __attribute__((ext_vector_type(8))) short s8v;    // 8 bf16
typedef __attribute__((ext_vector_type(4))) float f32x4;  // MFMA acc

__device__ __forceinline__ float sp_f(float v) {
  return fmaxf(v, 0.0f) + log1pf(__expf(-fabsf(v)));
}
__device__ __forceinline__ float tanh5_f(float v) {
  float a = fabsf(v);
  float e = __expf(-2.0f * a);
  float t = (1.0f - e) / (1.0f + e);
  return copysignf(5.0f * t, v);
}
__device__ __forceinline__ float lae_f(float a, float c) {
  float m = fmaxf(a, c);
  return m + log1pf(__expf(-fabsf(a - c)));
}
// RNE-pack two f32 into one uint holding 2 bf16 (lo=a, hi=b)
__device__ __forceinline__ unsigned pack2(float a, float b) {
  unsigned ua = __float_as_uint(a), ub = __float_as_uint(b);
  ua = (ua + 0x7fffu + ((ua >> 16) & 1u)) >> 16;
  ub = (ub + 0x7fffu + ((ub >> 16) & 1u)) & 0xffff0000u;
  return ua | ub;
}

// ---------- K1: lean R8-structure MFMA GEMM (single-chain bf16) ----------
// Block stages 16-row x-tiles (f32 global, fully coalesced 1KB/instr,
// issue-early/write-late), converts to bf16 at staging, stores in swizzled
// LDS. Waves split K (4 chunks of 32 each); cross-wave reduce in LDS; w0
// runs bias+activation epilogue. Read-ceiling-bound by design.
__global__ __launch_bounds__(256, 2)
void k1_lean(const float* __restrict__ x, const float* __restrict__ W,
             const float* __restrict__ bias, float* __restrict__ out) {
  __shared__ uint4 wp[16][64];       // 16 KB: W bf16, slot g^(row&7), g=k/8
  __shared__ uint4 xt[2][16][64];    // 32 KB: x bf16 tiles (dbuf), same swizzle
  __shared__ float4 red[2][3][64];   // 6 KB
  const int tid = threadIdx.x;

  // one-time W pack (coalesced read -> swizzled bf16 LDS)
  {
#pragma unroll
    for (int k = 0; k < 8; ++k) {
      const int f4i = tid + k * 256;          // 2048 float4 total
      const float4 v = *((const float4*)W + f4i);
      const int s = f4i >> 7;                 // row
      const int f = f4i & 127;                // float4 index in row = uint2 idx
      uint2 p; p.x = pack2(v.x, v.y); p.y = pack2(v.z, v.w);
      ((uint2*)&wp[s][0])[(((f >> 1) ^ (s & 7)) << 1) | (f & 1)] = p;
    }
  }
  __syncthreads();

  const int l = tid & 63;
  const int w = tid >> 6;
  const int lr = l & 15;        // fragment row (x-row in tile / out row)
  const int lk = (l >> 4) & 3;  // quarter -> output channel group
  const int r7 = lr & 7;

  const long rowbase = (long)blockIdx.x * 512;
  const float* __restrict__ xbase = x + rowbase * T_INSIZE;
  const float4 bv = *(const float4*)(bias + lk * 4);

  // stage tile 0
#pragma unroll
  for (int j = 0; j < 8; ++j) {
    const int q = w * 8 + j;                      // 64-float4 chunk
    const float4 v = *((const float4*)xbase + q * 64 + l);
    const int r = q >> 1;
    const int u = ((q & 1) << 6) | l;             // uint2 index in row
    uint2 p; p.x = pack2(v.x, v.y); p.y = pack2(v.z, v.w);
    ((uint2*)&xt[0][r][0])[(((u >> 1) ^ (r & 7)) << 1) | (u & 1)] = p;
  }
  __syncthreads();

  for (int t = 0; t < 32; ++t) {
    // issue next tile's loads early
    float4 stg[8];
    if (t + 1 < 32) {
      const float4* src = (const float4*)(xbase + (long)(t + 1) * 16 * T_INSIZE);
#pragma unroll
      for (int j = 0; j < 8; ++j) stg[j] = src[(w * 8 + j) * 64 + l];
    }

    // compute: wave w handles kc = w*4 .. w*4+3  (k = kc*32)
    const uint4 (*buf)[64] = xt[t & 1];
    f32x4 acc = {0.f, 0.f, 0.f, 0.f};
#pragma unroll
    for (int i = 0; i < 4; ++i) {
      const int g = (w * 4 + i) * 4 + lk;
      union { uint4 u; s8v v; } A, B;
      A.u = wp[lr][g ^ r7];
      B.u = buf[lr][g ^ r7];
      acc = __builtin_amdgcn_mfma_f32_16x16x32_bf16(A.v, B.v, acc, 0, 0, 0);
    }

    // write staged tile (bf16) into other buffer
    if (t + 1 < 32) {
      uint4 (*dst)[64] = xt[(t + 1) & 1];
#pragma unroll
      for (int j = 0; j < 8; ++j) {
        const int q = w * 8 + j;
        const int r = q >> 1;
        const int u = ((q & 1) << 6) | l;
        uint2 p; p.x = pack2(stg[j].x, stg[j].y); p.y = pack2(stg[j].z, stg[j].w);
        ((uint2*)&dst[r][0])[(((u >> 1) ^ (r & 7)) << 1) | (u & 1)] = p;
      }
    }

    // cross-wave partials
    if (w != 0) {
      float4 p; p.x = acc[0]; p.y = acc[1]; p.z = acc[2]; p.w = acc[3];
      red[t & 1][w - 1][l] = p;
    }
    __syncthreads();

    if (w == 0) {
      const float4 p1 = red[t & 1][0][l];
      const float4 p2 = red[t & 1][1][l];
      const float4 p3 = red[t & 1][2][l];
      const float y0 = acc[0] + p1.x + p2.x + p3.x + bv.x;
      const float y1 = acc[1] + p1.y + p2.y + p3.y + bv.y;
      const float y2 = acc[2] + p1.z + p2.z + p3.z + bv.z;
      const float y3 = acc[3] + p1.w + p2.w + p3.w + bv.w;
      float4 o;
      if (lk == 0) {
        o.x = 1.0f + sp_f(y0); o.y = 1.0f + sp_f(y1);
        o.z = 1.0f + sp_f(y2); o.w = 1.0f + sp_f(y3);
      } else if (lk == 1) {
        o.x = 0.1f + sp_f(y0); o.y = 0.1f + sp_f(y1);
        o.z = 0.1f + sp_f(y2); o.w = 0.1f + sp_f(y3);
      } else {
        o.x = tanh5_f(y0); o.y = tanh5_f(y1);
        o.z = tanh5_f(y2); o.w = tanh5_f(y3);
      }
      *(float4*)(out + (rowbase + (long)t * 16 + lr) * T_SIZE + lk * 4) = o;
    }
  }
}

// ---------- K2a: per-(b, chunk, basis-col) chunk transfer-matrix columns ----------
__global__ void k_scan_chunks(const float* __restrict__ out, float* __restrict__ mats,
                              int nchunks) {
  const int gtid = blockIdx.x * blockDim.x + threadIdx.x;
  const int colslot = gtid & 7;
  const int b = (gtid >> 3) & (T_NBATCH - 1);
  const int chunk = gtid >> 10;
  if (chunk >= nchunks) return;
  if (colslot >= 5) return;

  const int steps = T_NTIME / nchunks;
  const int t0 = chunk * steps;
  const float NEG = -1e30f;
  float f0 = (colslot == 0) ? 0.0f : NEG;
  float f1 = (colslot == 1) ? 0.0f : NEG;
  float f2 = (colslot == 2) ? 0.0f : NEG;
  float f3 = (colslot == 3) ? 0.0f : NEG;
  const float t4 = (colslot == 4) ? 0.0f : NEG;

  const long stride = T_NBATCH * T_SIZE;
  const float* p = out + ((long)t0 * T_NBATCH + b) * T_SIZE + 8;
  float4 mv = *(const float4*)(p);
  float4 st = *(const float4*)(p + 4);
  for (int s = 0; s < steps; ++s) {
    const float* pn = (s + 1 < steps) ? p + stride : p;
    const float4 mvn = *(const float4*)(pn);
    const float4 stn = *(const float4*)(pn + 4);

    float m, ss0, ss1, ss2, ss3;
    m = fmaxf(fmaxf(f1, f2), fmaxf(f3, t4));
    ss0 = m + __logf(__expf(f1 - m) + __expf(f2 - m) + __expf(f3 - m) + __expf(t4 - m));
    m = fmaxf(fmaxf(f0, f2), fmaxf(f3, t4));
    ss1 = m + __logf(__expf(f0 - m) + __expf(f2 - m) + __expf(f3 - m) + __expf(t4 - m));
    m = fmaxf(fmaxf(f0, f1), fmaxf(f3, t4));
    ss2 = m + __logf(__expf(f0 - m) + __expf(f1 - m) + __expf(f3 - m) + __expf(t4 - m));
    m = fmaxf(fmaxf(f0, f1), fmaxf(f2, t4));
    ss3 = m + __logf(__expf(f0 - m) + __expf(f1 - m) + __expf(f2 - m) + __expf(t4 - m));

    const float n0 = lae_f(f0 + st.x, ss0 + mv.x);
    const float n1 = lae_f(f1 + st.y, ss1 + mv.y);
    const float n2 = lae_f(f2 + st.z, ss2 + mv.z);
    const float n3 = lae_f(f3 + st.w, ss3 + mv.w);
    f0 = n0; f1 = n1; f2 = n2; f3 = n3;
    mv = mvn; st = stn; p = pn;
  }
  float* d = mats + ((long)chunk * T_NBATCH + b) * MAT_STRIDE + colslot * 4;
  float4 o; o.x = f0; o.y = f1; o.z = f2; o.w = f3;
  *(float4*)d = o;
}

// ---------- K2b: serial combine of chunk matrices per batch; logZ/T out ----------
__global__ void k_combine(const float* __restrict__ mats, float* __restrict__ logz,
                          int nchunks) {
  const int tid = threadIdx.x;
  const int i = tid & 3;
  const int b = tid >> 2;
  if (b >= T_NBATCH) return;
  float v = 0.0f;

  const float* Tb = mats + (long)b * MAT_STRIDE;
  const long cstride = (long)T_NBATCH * MAT_STRIDE;
  float q0 = Tb[i * 4 + i];
  float q1 = Tb[((i ^ 1) * 4) + i];
  float q2 = Tb[((i ^ 2) * 4) + i];
  float q3 = Tb[((i ^ 3) * 4) + i];
  float q4 = Tb[16 + i];
  for (int c = 0; c < nchunks; ++c) {
    const float* Tn = Tb + cstride;
    float n0 = 0, n1 = 0, n2 = 0, n3 = 0, n4 = 0;
    if (c + 1 < nchunks) {
      n0 = Tn[i * 4 + i];
      n1 = Tn[((i ^ 1) * 4) + i];
      n2 = Tn[((i ^ 2) * 4) + i];
      n3 = Tn[((i ^ 3) * 4) + i];
      n4 = Tn[16 + i];
    }
    const float vx1 = __shfl_xor(v, 1);
    const float vx2 = __shfl_xor(v, 2);
    const float vx3 = __shfl_xor(v, 3);
    const float a0 = q0 + v;
    const float a1 = q1 + vx1;
    const float a2 = q2 + vx2;
    const float a3 = q3 + vx3;
    const float a4 = q4;
    float m = fmaxf(fmaxf(a0, a1), fmaxf(fmaxf(a2, a3), a4));
    v = m + __logf(__expf(a0 - m) + __expf(a1 - m) + __expf(a2 - m) +
                   __expf(a3 - m) + __expf(a4 - m));
    q0 = n0; q1 = n1; q2 = n2; q3 = n3; q4 = n4;
    Tb = Tn;
  }
  float m1 = fmaxf(v, __shfl_xor(v, 1));
  m1 = fmaxf(m1, __shfl_xor(m1, 2));
  float e = __expf(v - m1);
  e += __shfl_xor(e, 1);
  e += __shfl_xor(e, 2);
  const float lz = m1 + __logf(e);
  if (i == 0) logz[b] = lz * (1.0f / (float)T_NTIME);
}

// ---------- K3: out[t][b][8..15] -= logZ[b]/T ----------
__global__ void k_sub(float* __restrict__ out, const float* __restrict__ logz) {
  const long n = (long)blockIdx.x * blockDim.x + threadIdx.x;
  if (n >= (long)T_NROWS * 2) return;
  const long tb = n >> 1;
  const int b = (int)(tb & (T_NBATCH - 1));
  const float lz = logz[b];
  float4* p = (float4*)(out + tb * T_SIZE + 8 + (n & 1) * 4);
  float4 v = *p;
  v.x -= lz; v.y -= lz; v.z -= lz; v.w -= lz;
  *p = v;
}

extern "C" void kernel_launch(void* const* d_in, const int* in_sizes, int n_in,
                              void* d_out, int out_size, void* d_ws, size_t ws_size,
                              hipStream_t stream) {
  const float* x    = (const float*)d_in[0];
  const float* W    = (const float*)d_in[1];
  const float* bias = (const float*)d_in[2];
  float* out = (float*)d_out;
  float* ws  = (float*)d_ws;

  int C = NCHUNK;
  while (C > 1 && (size_t)((long)C * T_NBATCH * MAT_STRIDE + T_NBATCH) * 4 > ws_size) C >>= 1;
  float* mats = ws;
  float* logz = ws + (long)C * T_NBATCH * MAT_STRIDE;

  k1_lean<<<T_NROWS / 512, 256, 0, stream>>>(x, W, bias, out);

  const int thr2 = C * T_NBATCH * 8;
  k_scan_chunks<<<thr2 / 256, 256, 0, stream>>>(out, mats, C);
  k_combine<<<1, 512, 0, stream>>>(mats, logz, C);
  k_sub<<<(T_NROWS * 2) / 256, 256, 0, stream>>>(out, logz);
}

// Round 13
// 198.786 us; speedup vs baseline: 1.1462x; 1.1175x over previous
//
#include <hip/hip_runtime.h>
#include <math.h>

#define T_NTIME  2048
#define T_NBATCH 128
#define T_INSIZE 512
#define T_SIZE   16
#define T_NROWS  (T_NTIME * T_NBATCH)
#define MAT_STRIDE 24

typedef __attribute__((ext_vector_type(8))) short s8v;    // 8 bf16 (4 VGPR)
typedef __attribute__((ext_vector_type(4))) float f32x4;  // MFMA acc

__device__ __forceinline__ float sp_f(float v) {
  return fmaxf(v, 0.0f) + log1pf(__expf(-fabsf(v)));
}
__device__ __forceinline__ float tanh5_f(float v) {
  float a = fabsf(v);
  float e = __expf(-2.0f * a);
  float t = (1.0f - e) / (1.0f + e);
  return copysignf(5.0f * t, v);
}
__device__ __forceinline__ float lae_f(float a, float c) {
  float m = fmaxf(a, c);
  return m + log1pf(__expf(-fabsf(a - c)));
}
// round-to-nearest-even f32 -> bf16 bits, and the exact residual
__device__ __forceinline__ void bf16_split(float f, short& hi, short& lo) {
  unsigned u = __float_as_uint(f);
  unsigned hb = (u + 0x7fffu + ((u >> 16) & 1u)) >> 16;
  float hf = __uint_as_float(hb << 16);
  float l = f - hf;
  unsigned ul = __float_as_uint(l);
  unsigned lb = (ul + 0x7fffu + ((ul >> 16) & 1u)) >> 16;
  hi = (short)hb;
  lo = (short)lb;
}

// ---------- K1: MFMA GEMM  out = act(x @ W^T + b), trans pre-logZ ----------
// (R8 structure — best measured: 199us, K1 ~= 3.15 TB/s read = fabric read
// ceiling.) 16-row x-tiles staged in LDS (dbuf), coalesced reg-staging (lane
// reads consecutive float4 -> linear HBM stream), XOR-swizzled LDS slots.
// bf16 hi/lo split => f32-grade accuracy. Wave w owns k-chunks [4w,4w+4);
// W A-frags resident in VGPRs; cross-wave reduce in LDS (parity dbuf);
// wave0 activates + stores.
__global__ __launch_bounds__(256, 2)
void k1_mfma(const float* __restrict__ x, const float* __restrict__ W,
             const float* __restrict__ bias, float* __restrict__ out) {
  __shared__ float4 xb[2][2048];     // 2 x 16 rows x 128 chunks (64 KB)
  __shared__ float4 red[2][3][64];   // 6 KB
  const int tid = threadIdx.x;
  const int l = tid & 63;
  const int w = tid >> 6;
  const int lr = l & 15;   // x-row within tile (B n-index) / W s-row (A m-index)
  const int lk = l >> 4;   // k-subgroup 0..3
  const int r7 = lr & 7;

  // one-time: A-frags of W (hi/lo) for this wave's 4 k-chunks
  s8v ah[4], al[4];
#pragma unroll
  for (int kc2 = 0; kc2 < 4; ++kc2) {
    const float* wp = W + lr * T_INSIZE + (w * 4 + kc2) * 32 + lk * 8;
    const float4 a0 = *(const float4*)(wp);
    const float4 a1 = *(const float4*)(wp + 4);
    const float f[8] = {a0.x, a0.y, a0.z, a0.w, a1.x, a1.y, a1.z, a1.w};
#pragma unroll
    for (int j = 0; j < 8; ++j) {
      short h, lo2; bf16_split(f[j], h, lo2);
      ah[kc2][j] = h; al[kc2][j] = lo2;
    }
  }
  const float4 bv = *(const float4*)(bias + lk * 4);

  const long rowbase = (long)blockIdx.x * 512;
  const float* xbase = x + rowbase * T_INSIZE;

  // prologue: stage tile 0 (coalesced load -> swizzled LDS write)
#pragma unroll
  for (int j = 0; j < 8; ++j) {
    const int q = w * 8 + j;
    const float4 v = *(const float4*)(xbase + q * 256 + l * 4);
    const int r = q >> 1;
    const int c = ((q & 1) << 6) | l;
    xb[0][r * 128 + (c ^ (r & 7))] = v;
  }
  __syncthreads();

  for (int t = 0; t < 32; ++t) {
    // issue next tile's global loads early (fly under compute)
    float4 stg0, stg1, stg2, stg3, stg4, stg5, stg6, stg7;
    if (t + 1 < 32) {
      const float* src = xbase + (long)(t + 1) * 16 * T_INSIZE;
      const int q0 = w * 8;
      stg0 = *(const float4*)(src + (q0 + 0) * 256 + l * 4);
      stg1 = *(const float4*)(src + (q0 + 1) * 256 + l * 4);
      stg2 = *(const float4*)(src + (q0 + 2) * 256 + l * 4);
      stg3 = *(const float4*)(src + (q0 + 3) * 256 + l * 4);
      stg4 = *(const float4*)(src + (q0 + 4) * 256 + l * 4);
      stg5 = *(const float4*)(src + (q0 + 5) * 256 + l * 4);
      stg6 = *(const float4*)(src + (q0 + 6) * 256 + l * 4);
      stg7 = *(const float4*)(src + (q0 + 7) * 256 + l * 4);
    }

    // compute tile t
    const float4* bufp = xb[t & 1];
    f32x4 acc = {0.f, 0.f, 0.f, 0.f};
#pragma unroll
    for (int kc2 = 0; kc2 < 4; ++kc2) {
      const int cbase = (w * 4 + kc2) * 8 + lk * 2;
      const float4 b0 = bufp[lr * 128 + (cbase ^ r7)];
      const float4 b1 = bufp[lr * 128 + ((cbase + 1) ^ r7)];
      s8v bh, bl2;
      const float f[8] = {b0.x, b0.y, b0.z, b0.w, b1.x, b1.y, b1.z, b1.w};
#pragma unroll
      for (int j = 0; j < 8; ++j) {
        short h, lo2; bf16_split(f[j], h, lo2);
        bh[j] = h; bl2[j] = lo2;
      }
      acc = __builtin_amdgcn_mfma_f32_16x16x32_bf16(ah[kc2], bh, acc, 0, 0, 0);
      acc = __builtin_amdgcn_mfma_f32_16x16x32_bf16(ah[kc2], bl2, acc, 0, 0, 0);
      acc = __builtin_amdgcn_mfma_f32_16x16x32_bf16(al[kc2], bh, acc, 0, 0, 0);
    }

    // late LDS write of the staged tile into the other buffer
    if (t + 1 < 32) {
      float4* dst = xb[(t + 1) & 1];
      const int q0 = w * 8;
#define STW(J, V)                                                   \
      { const int q = q0 + (J); const int r = q >> 1;               \
        const int c = ((q & 1) << 6) | l;                           \
        dst[r * 128 + (c ^ (r & 7))] = (V); }
      STW(0, stg0) STW(1, stg1) STW(2, stg2) STW(3, stg3)
      STW(4, stg4) STW(5, stg5) STW(6, stg6) STW(7, stg7)
#undef STW
    }

    // cross-wave partials
    if (w != 0) {
      float4 p; p.x = acc[0]; p.y = acc[1]; p.z = acc[2]; p.w = acc[3];
      red[t & 1][w - 1][l] = p;
    }
    __syncthreads();

    if (w == 0) {
      const float4 p1 = red[t & 1][0][l];
      const float4 p2 = red[t & 1][1][l];
      const float4 p3 = red[t & 1][2][l];
      const float y0 = acc[0] + p1.x + p2.x + p3.x + bv.x;
      const float y1 = acc[1] + p1.y + p2.y + p3.y + bv.y;
      const float y2 = acc[2] + p1.z + p2.z + p3.z + bv.z;
      const float y3 = acc[3] + p1.w + p2.w + p3.w + bv.w;
      float4 o;
      if (lk == 0) {
        o.x = 1.0f + sp_f(y0); o.y = 1.0f + sp_f(y1);
        o.z = 1.0f + sp_f(y2); o.w = 1.0f + sp_f(y3);
      } else if (lk == 1) {
        o.x = 0.1f + sp_f(y0); o.y = 0.1f + sp_f(y1);
        o.z = 0.1f + sp_f(y2); o.w = 0.1f + sp_f(y3);
      } else {
        o.x = tanh5_f(y0); o.y = tanh5_f(y1);
        o.z = tanh5_f(y2); o.w = tanh5_f(y3);
      }
      *(float4*)(out + (rowbase + (long)t * 16 + lr) * T_SIZE + lk * 4) = o;
    }
  }
}

// ---------- K2a: per-(b, chunk, basis-col) chunk transfer-matrix columns ----------
__global__ void k_scan_chunks(const float* __restrict__ out, float* __restrict__ mats,
                              int nchunks) {
  const int gtid = blockIdx.x * blockDim.x + threadIdx.x;
  const int colslot = gtid & 7;
  const int b = (gtid >> 3) & (T_NBATCH - 1);
  const int chunk = gtid >> 10;
  if (chunk >= nchunks) return;
  if (colslot >= 5) return;

  const int steps = T_NTIME / nchunks;
  const int t0 = chunk * steps;
  const float NEG = -1e30f;
  float f0 = (colslot == 0) ? 0.0f : NEG;
  float f1 = (colslot == 1) ? 0.0f : NEG;
  float f2 = (colslot == 2) ? 0.0f : NEG;
  float f3 = (colslot == 3) ? 0.0f : NEG;
  const float t4 = (colslot == 4) ? 0.0f : NEG;

  const long stride = T_NBATCH * T_SIZE;
  const float* p = out + ((long)t0 * T_NBATCH + b) * T_SIZE + 8;
  float4 mv = *(const float4*)(p);
  float4 st = *(const float4*)(p + 4);
  for (int s = 0; s < steps; ++s) {
    const float* pn = (s + 1 < steps) ? p + stride : p;
    const float4 mvn = *(const float4*)(pn);
    const float4 stn = *(const float4*)(pn + 4);

    float m, ss0, ss1, ss2, ss3;
    m = fmaxf(fmaxf(f1, f2), fmaxf(f3, t4));
    ss0 = m + __logf(__expf(f1 - m) + __expf(f2 - m) + __expf(f3 - m) + __expf(t4 - m));
    m = fmaxf(fmaxf(f0, f2), fmaxf(f3, t4));
    ss1 = m + __logf(__expf(f0 - m) + __expf(f2 - m) + __expf(f3 - m) + __expf(t4 - m));
    m = fmaxf(fmaxf(f0, f1), fmaxf(f3, t4));
    ss2 = m + __logf(__expf(f0 - m) + __expf(f1 - m) + __expf(f3 - m) + __expf(t4 - m));
    m = fmaxf(fmaxf(f0, f1), fmaxf(f2, t4));
    ss3 = m + __logf(__expf(f0 - m) + __expf(f1 - m) + __expf(f2 - m) + __expf(t4 - m));

    const float n0 = lae_f(f0 + st.x, ss0 + mv.x);
    const float n1 = lae_f(f1 + st.y, ss1 + mv.y);
    const float n2 = lae_f(f2 + st.z, ss2 + mv.z);
    const float n3 = lae_f(f3 + st.w, ss3 + mv.w);
    f0 = n0; f1 = n1; f2 = n2; f3 = n3;
    mv = mvn; st = stn; p = pn;
  }
  float* d = mats + ((long)chunk * T_NBATCH + b) * MAT_STRIDE + colslot * 4;
  float4 o; o.x = f0; o.y = f1; o.z = f2; o.w = f3;
  *(float4*)d = o;
}

// ---------- K2b: serial combine of chunk matrices per batch; logZ/T out ----------
__global__ void k_combine(const float* __restrict__ mats, float* __restrict__ logz,
                          int nchunks) {
  const int tid = threadIdx.x;
  const int i = tid & 3;
  const int b = tid >> 2;
  if (b >= T_NBATCH) return;
  float v = 0.0f;

  const float* Tb = mats + (long)b * MAT_STRIDE;
  const long cstride = (long)T_NBATCH * MAT_STRIDE;
  float q0 = Tb[i * 4 + i];
  float q1 = Tb[((i ^ 1) * 4) + i];
  float q2 = Tb[((i ^ 2) * 4) + i];
  float q3 = Tb[((i ^ 3) * 4) + i];
  float q4 = Tb[16 + i];
  for (int c = 0; c < nchunks; ++c) {
    const float* Tn = Tb + cstride;
    float n0 = 0, n1 = 0, n2 = 0, n3 = 0, n4 = 0;
    if (c + 1 < nchunks) {
      n0 = Tn[i * 4 + i];
      n1 = Tn[((i ^ 1) * 4) + i];
      n2 = Tn[((i ^ 2) * 4) + i];
      n3 = Tn[((i ^ 3) * 4) + i];
      n4 = Tn[16 + i];
    }
    const float vx1 = __shfl_xor(v, 1);
    const float vx2 = __shfl_xor(v, 2);
    const float vx3 = __shfl_xor(v, 3);
    const float a0 = q0 + v;
    const float a1 = q1 + vx1;
    const float a2 = q2 + vx2;
    const float a3 = q3 + vx3;
    const float a4 = q4;
    float m = fmaxf(fmaxf(a0, a1), fmaxf(fmaxf(a2, a3), a4));
    v = m + __logf(__expf(a0 - m) + __expf(a1 - m) + __expf(a2 - m) +
                   __expf(a3 - m) + __expf(a4 - m));
    q0 = n0; q1 = n1; q2 = n2; q3 = n3; q4 = n4;
    Tb = Tn;
  }
  float m1 = fmaxf(v, __shfl_xor(v, 1));
  m1 = fmaxf(m1, __shfl_xor(m1, 2));
  float e = __expf(v - m1);
  e += __shfl_xor(e, 1);
  e += __shfl_xor(e, 2);
  const float lz = m1 + __logf(e);
  if (i == 0) logz[b] = lz * (1.0f / (float)T_NTIME);
}

// ---------- K3: out[t][b][8..15] -= logZ[b]/T ----------
__global__ void k_sub(float* __restrict__ out, const float* __restrict__ logz) {
  const long n = (long)blockIdx.x * blockDim.x + threadIdx.x;
  if (n >= (long)T_NROWS * 2) return;
  const long tb = n >> 1;
  const int b = (int)(tb & (T_NBATCH - 1));
  const float lz = logz[b];
  float4* p = (float4*)(out + tb * T_SIZE + 8 + (n & 1) * 4);
  float4 v = *p;
  v.x -= lz; v.y -= lz; v.z -= lz; v.w -= lz;
  *p = v;
}

extern "C" void kernel_launch(void* const* d_in, const int* in_sizes, int n_in,
                              void* d_out, int out_size, void* d_ws, size_t ws_size,
                              hipStream_t stream) {
  const float* x    = (const float*)d_in[0];
  const float* W    = (const float*)d_in[1];
  const float* bias = (const float*)d_in[2];
  float* out = (float*)d_out;
  float* ws  = (float*)d_ws;

  int C = 64;
  while (C > 1 && (size_t)((long)C * T_NBATCH * MAT_STRIDE + T_NBATCH) * 4 > ws_size) C >>= 1;
  float* mats = ws;
  float* logz = ws + (long)C * T_NBATCH * MAT_STRIDE;

  k1_mfma<<<T_NROWS / 512, 256, 0, stream>>>(x, W, bias, out);

  const int thr2 = C * T_NBATCH * 8;
  k_scan_chunks<<<thr2 / 256, 256, 0, stream>>>(out, mats, C);
  k_combine<<<1, 512, 0, stream>>>(mats, logz, C);
  k_sub<<<(T_NROWS * 2) / 256, 256, 0, stream>>>(out, logz);
}